// Round 1
// baseline (1825.903 us; speedup 1.0000x reference)
//
#include <hip/hip_runtime.h>
#include <math.h>

#define BB   8      // batches
#define NN   4096   // points per batch
#define DD   3
#define MAXK 16
#define BQ   256    // threads per block = queries per block
#define CH   1024   // candidate chunk staged in LDS (float4 = 16 KB)

// One thread per query point. Whole candidate set streamed through LDS in
// chunks; every lane of a wave reads the same candidate (LDS broadcast, no
// bank conflicts). Top-k (k<=16) kept in registers; all per-lane array
// indexing is compile-time constant after full unroll (runtime slot selection
// done with predicated writes) so nothing spills to scratch.
__global__ __launch_bounds__(BQ) void knn_mean_kernel(
    const float* __restrict__ x,
    const float* __restrict__ preds,
    const float* __restrict__ kvec,
    float* __restrict__ out)
{
    // k = argmax(k_vector) + 1, first index wins ties (jnp.argmax semantics).
    float bv = kvec[0];
    int bi = 0;
#pragma unroll
    for (int i = 1; i < MAXK; ++i) {
        float v = kvec[i];
        if (v > bv) { bv = v; bi = i; }
    }
    const int k = bi + 1;            // wave-uniform

    const int b  = blockIdx.x / (NN / BQ);
    const int q0 = (blockIdx.x % (NN / BQ)) * BQ;
    const int qi = q0 + (int)threadIdx.x;

    const float* xb = x + (size_t)b * NN * DD;

    // Query coords + squared norm, replicating reference fp32 op order
    // (no FMA contraction anywhere: use explicit _rn intrinsics).
    const float qx = xb[qi * 3 + 0];
    const float qy = xb[qi * 3 + 1];
    const float qz = xb[qi * 3 + 2];
    const float qsq = __fadd_rn(__fadd_rn(__fmul_rn(qx, qx), __fmul_rn(qy, qy)),
                                __fmul_rn(qz, qz));

    __shared__ float4 cand[CH];

    // Top-k list in registers. Sentinels: d2=+inf, idx = big and increasing
    // with slot so the lexicographic-max eviction rule drains high slots first.
    float bd2[MAXK];
    int   bix[MAXK];
#pragma unroll
    for (int s = 0; s < MAXK; ++s) { bd2[s] = INFINITY; bix[s] = 0x40000000 + s; }
    float wd2   = INFINITY;   // current lexicographic max (d2, idx) among slots < k
    int   wslot = k - 1;      // its slot (largest sentinel idx among the k infs)

    for (int j0 = 0; j0 < NN; j0 += CH) {
        __syncthreads();
        // Cooperative stage of CH candidates: (cx, cy, cz, csq)
        for (int t = (int)threadIdx.x; t < CH; t += BQ) {
            const int j = j0 + t;
            const float cx = xb[j * 3 + 0];
            const float cy = xb[j * 3 + 1];
            const float cz = xb[j * 3 + 2];
            const float csq = __fadd_rn(__fadd_rn(__fmul_rn(cx, cx), __fmul_rn(cy, cy)),
                                        __fmul_rn(cz, cz));
            cand[t] = make_float4(cx, cy, cz, csq);
        }
        __syncthreads();

        for (int t = 0; t < CH; ++t) {
            const float4 c = cand[t];                       // wave-uniform broadcast
            const float inner = __fadd_rn(
                __fadd_rn(__fmul_rn(qx, c.x), __fmul_rn(qy, c.y)),
                __fmul_rn(qz, c.z));
            float d2 = __fsub_rn(__fadd_rn(qsq, c.w), __fmul_rn(2.0f, inner));
            d2 = fmaxf(d2, 0.0f);

            // Strict < implements top_k's lower-index-wins tie rule, since we
            // stream candidates in ascending index order.
            if (d2 < wd2) {
                const int j = j0 + t;
                // Replace slot `wslot` with (d2, j), recompute lexicographic
                // max among slots < k. Fully unrolled; all reg indexing static.
                float nwd2 = -1.0f; int nwix = -1; int nwslot = 0;
#pragma unroll
                for (int s = 0; s < MAXK; ++s) {
                    if (s < k) {
                        const bool repl = (s == wslot);
                        const float sd2 = repl ? d2 : bd2[s];
                        const int   six = repl ? j  : bix[s];
                        if (repl) { bd2[s] = d2; bix[s] = j; }
                        if (sd2 > nwd2 || (sd2 == nwd2 && six > nwix)) {
                            nwd2 = sd2; nwix = six; nwslot = s;
                        }
                    }
                }
                wd2 = nwd2; wslot = nwslot;
            }
        }
    }

    // Mean of preds over the k selected neighbors. Slot order differs from the
    // reference's distance-sorted order — only ulp-level rounding differences.
    const float* pb = preds + (size_t)b * NN * DD;
    float sx = 0.0f, sy = 0.0f, sz = 0.0f;
#pragma unroll
    for (int s = 0; s < MAXK; ++s) {
        if (s < k) {
            const int j = bix[s];
            sx = __fadd_rn(sx, pb[j * 3 + 0]);
            sy = __fadd_rn(sy, pb[j * 3 + 1]);
            sz = __fadd_rn(sz, pb[j * 3 + 2]);
        }
    }
    const float fk = (float)k;
    float* ob = out + (size_t)b * NN * DD;
    ob[qi * 3 + 0] = __fdiv_rn(sx, fk);
    ob[qi * 3 + 1] = __fdiv_rn(sy, fk);
    ob[qi * 3 + 2] = __fdiv_rn(sz, fk);
}

extern "C" void kernel_launch(void* const* d_in, const int* in_sizes, int n_in,
                              void* d_out, int out_size, void* d_ws, size_t ws_size,
                              hipStream_t stream) {
    (void)in_sizes; (void)n_in; (void)d_ws; (void)ws_size; (void)out_size;
    const float* x     = (const float*)d_in[0];
    const float* preds = (const float*)d_in[1];
    const float* kvec  = (const float*)d_in[2];
    float* out = (float*)d_out;

    const int grid = BB * (NN / BQ);   // 8 * 16 = 128 blocks
    knn_mean_kernel<<<grid, BQ, 0, stream>>>(x, preds, kvec, out);
}

// Round 2
// 163.643 us; speedup vs baseline: 11.1579x; 11.1579x over previous
//
#include <hip/hip_runtime.h>
#include <math.h>

typedef unsigned long long u64;
typedef unsigned int u32;

#define BB 8
#define NN 4096
#define MAXK 16
#define NSEG 4
#define BQ 64          // one wave per block
#define CHUNK 512      // candidates staged per LDS pass (8 KB)
#define BUFSLOTS 16    // per-lane append buffer (8 KB)

// Branch-free sorted insert of `key` into ascending 16-entry u64 `list`.
// Precondition (enforced by caller): key < list[MAXK-1].
// Keys are unique ((d2_bits<<32)|idx with unique idx), so no tie handling.
#define INSERT16(KEYV) do {                                                  \
    bool c_[MAXK];                                                           \
    _Pragma("unroll")                                                        \
    for (int s_ = 0; s_ < MAXK; ++s_) c_[s_] = (KEYV) < list[s_];            \
    _Pragma("unroll")                                                        \
    for (int s_ = MAXK - 1; s_ >= 1; --s_)                                   \
        list[s_] = c_[s_] ? (c_[s_ - 1] ? list[s_ - 1] : (KEYV)) : list[s_]; \
    list[0] = c_[0] ? (KEYV) : list[0];                                      \
    wkey = list[MAXK - 1];                                                   \
} while (0)

// Drain the per-lane LDS append buffer into the register list.
#define FLUSH() do {                                                         \
    _Pragma("unroll")                                                        \
    for (int i_ = 0; i_ < BUFSLOTS; ++i_) {                                  \
        const u64 fk_ = buf[i_][lane];                                       \
        if (i_ < cnt && fk_ < wkey) { INSERT16(fk_); }                       \
    }                                                                        \
    cnt = 0;                                                                 \
} while (0)

template <int SEGS, bool FUSED>
__global__ __launch_bounds__(BQ) void knn_scan(
    const float* __restrict__ x, const float* __restrict__ preds,
    const float* __restrict__ kvec, u64* __restrict__ ws,
    float* __restrict__ out)
{
    constexpr int SEGLEN = NN / SEGS;
    int bid = blockIdx.x;
    const int seg = bid % SEGS; bid /= SEGS;
    const int qg  = bid % (NN / BQ);
    const int b   = bid / (NN / BQ);
    const int lane = (int)threadIdx.x;
    const int qi = qg * BQ + lane;

    const float* xb = x + (size_t)b * NN * 3;
    const float qx = xb[qi * 3 + 0];
    const float qy = xb[qi * 3 + 1];
    const float qz = xb[qi * 3 + 2];
    // Reference fp32 op order, no FMA contraction (matches np einsum/ufuncs).
    const float qsq = __fadd_rn(__fadd_rn(__fmul_rn(qx, qx), __fmul_rn(qy, qy)),
                                __fmul_rn(qz, qz));

    __shared__ float4 cand[CHUNK];          // (cx, cy, cz, csq)
    __shared__ u64 buf[BUFSLOTS][BQ];       // [slot][lane] -> conflict-free

    u64 list[MAXK];
#pragma unroll
    for (int s = 0; s < MAXK; ++s) list[s] = ~0ull;
    u64 wkey = ~0ull;
    int cnt = 0;

    const int jbase = seg * SEGLEN;
    for (int c0 = 0; c0 < SEGLEN; c0 += CHUNK) {
        __syncthreads();
        for (int t = lane; t < CHUNK; t += BQ) {
            const int j = jbase + c0 + t;
            const float cx = xb[j * 3 + 0];
            const float cy = xb[j * 3 + 1];
            const float cz = xb[j * 3 + 2];
            const float csq = __fadd_rn(
                __fadd_rn(__fmul_rn(cx, cx), __fmul_rn(cy, cy)),
                __fmul_rn(cz, cz));
            cand[t] = make_float4(cx, cy, cz, csq);
        }
        __syncthreads();

        for (int t = 0; t < CHUNK; t += 4) {
            // Wave-uniform flush check: max 4 appends per batch, cnt <= 12 here.
            if (__any((int)(cnt > BUFSLOTS - 4))) { FLUSH(); }
#pragma unroll
            for (int u = 0; u < 4; ++u) {
                const float4 c = cand[t + u];           // wave-uniform broadcast
                const float inner = __fadd_rn(
                    __fadd_rn(__fmul_rn(qx, c.x), __fmul_rn(qy, c.y)),
                    __fmul_rn(qz, c.z));
                float d2 = __fsub_rn(__fadd_rn(qsq, c.w), __fmul_rn(2.0f, inner));
                d2 = fmaxf(d2, 0.0f);
                const u64 key = ((u64)__float_as_uint(d2) << 32)
                              | (u32)(jbase + c0 + t + u);
                // Branch-free append: always write at cnt, advance only on pass.
                buf[cnt][lane] = key;
                cnt += (key < wkey) ? 1 : 0;
            }
        }
    }
    FLUSH();

    if (FUSED) {
        // k = argmax(k_vector) + 1 (first index wins ties).
        float bv = kvec[0]; int bi = 0;
#pragma unroll
        for (int i = 1; i < MAXK; ++i) { const float v = kvec[i]; if (v > bv) { bv = v; bi = i; } }
        const int k = bi + 1;
        const float* pb = preds + (size_t)b * NN * 3;
        float sx = 0.f, sy = 0.f, sz = 0.f;
#pragma unroll
        for (int s = 0; s < MAXK; ++s) {
            if (s < k) {
                const int j = (int)(u32)list[s];
                sx = __fadd_rn(sx, pb[j * 3 + 0]);
                sy = __fadd_rn(sy, pb[j * 3 + 1]);
                sz = __fadd_rn(sz, pb[j * 3 + 2]);
            }
        }
        const float fk = (float)k;
        float* ob = out + ((size_t)b * NN + qi) * 3;
        ob[0] = __fdiv_rn(sx, fk);
        ob[1] = __fdiv_rn(sy, fk);
        ob[2] = __fdiv_rn(sz, fk);
    } else {
        // ws layout [SEGS*MAXK][B*N]: coalesced writes here, coalesced reads in merge.
        const size_t q = (size_t)b * NN + qi;
#pragma unroll
        for (int s = 0; s < MAXK; ++s)
            ws[(size_t)(seg * MAXK + s) * (BB * NN) + q] = list[s];
    }
}

__global__ __launch_bounds__(BQ) void knn_merge(
    const float* __restrict__ preds, const float* __restrict__ kvec,
    const u64* __restrict__ ws, float* __restrict__ out)
{
    const int q = blockIdx.x * BQ + (int)threadIdx.x;   // 0 .. B*N-1

    u64 list[MAXK];
#pragma unroll
    for (int s = 0; s < MAXK; ++s) list[s] = ~0ull;
    u64 wkey = ~0ull;

#pragma unroll 4
    for (int i = 0; i < NSEG * MAXK; ++i) {
        const u64 key = ws[(size_t)i * (BB * NN) + q];  // coalesced
        if (key < wkey) { INSERT16(key); }
    }

    float bv = kvec[0]; int bi = 0;
#pragma unroll
    for (int i = 1; i < MAXK; ++i) { const float v = kvec[i]; if (v > bv) { bv = v; bi = i; } }
    const int k = bi + 1;

    const int b = q / NN;
    const float* pb = preds + (size_t)b * NN * 3;
    float sx = 0.f, sy = 0.f, sz = 0.f;
#pragma unroll
    for (int s = 0; s < MAXK; ++s) {
        if (s < k) {
            const int j = (int)(u32)list[s];
            sx = __fadd_rn(sx, pb[j * 3 + 0]);
            sy = __fadd_rn(sy, pb[j * 3 + 1]);
            sz = __fadd_rn(sz, pb[j * 3 + 2]);
        }
    }
    const float fk = (float)k;
    out[(size_t)q * 3 + 0] = __fdiv_rn(sx, fk);
    out[(size_t)q * 3 + 1] = __fdiv_rn(sy, fk);
    out[(size_t)q * 3 + 2] = __fdiv_rn(sz, fk);
}

extern "C" void kernel_launch(void* const* d_in, const int* in_sizes, int n_in,
                              void* d_out, int out_size, void* d_ws, size_t ws_size,
                              hipStream_t stream) {
    (void)in_sizes; (void)n_in; (void)out_size;
    const float* x     = (const float*)d_in[0];
    const float* preds = (const float*)d_in[1];
    const float* kvec  = (const float*)d_in[2];
    float* out = (float*)d_out;

    const size_t ws_need = (size_t)NSEG * MAXK * BB * NN * sizeof(u64);  // 16 MB
    if (ws_size >= ws_need) {
        u64* ws = (u64*)d_ws;
        knn_scan<NSEG, false><<<BB * (NN / BQ) * NSEG, BQ, 0, stream>>>(
            x, preds, kvec, ws, out);
        knn_merge<<<(BB * NN) / BQ, BQ, 0, stream>>>(preds, kvec, ws, out);
    } else {
        // Fallback: monolithic single-kernel variant, no workspace needed.
        knn_scan<1, true><<<BB * (NN / BQ), BQ, 0, stream>>>(
            x, preds, kvec, nullptr, out);
    }
}

// Round 3
// 158.478 us; speedup vs baseline: 11.5215x; 1.0326x over previous
//
#include <hip/hip_runtime.h>
#include <math.h>

typedef unsigned long long u64;
typedef unsigned int u32;

#define BB 8
#define NN 4096
#define MAXK 16
#define BQ 64          // one wave per block
#define BUFSLOTS 16    // per-lane LDS append buffer (8 KB/block)

// ---- branch-free in-register top-16 machinery (u64 keys, ascending) ----

// Bitonic sort 16 u64 regs ascending. All indices compile-time.
__device__ __forceinline__ void bitonic16(u64 v[MAXK]) {
#pragma unroll
    for (int k = 2; k <= 16; k <<= 1) {
#pragma unroll
        for (int j = k >> 1; j > 0; j >>= 1) {
#pragma unroll
            for (int i = 0; i < 16; ++i) {
                const int l = i ^ j;
                if (l > i) {
                    const u64 a = v[i], b = v[l];
                    const bool up = ((i & k) == 0);
                    const bool sw = up ? (a > b) : (a < b);
                    v[i] = sw ? b : a;
                    v[l] = sw ? a : b;
                }
            }
        }
    }
}

// list asc + br asc -> list = 16 smallest of the union, ascending.
__device__ __forceinline__ void merge16(u64 list[MAXK], const u64 br[MAXK]) {
    u64 lo[MAXK];
#pragma unroll
    for (int i = 0; i < 16; ++i) {
        const u64 a = list[i], b = br[15 - i];
        lo[i] = a < b ? a : b;              // lower half of bitonic(32); bitonic
    }
#pragma unroll
    for (int j = 8; j > 0; j >>= 1) {       // bitonic clean, ascending
#pragma unroll
        for (int i = 0; i < 16; ++i) {
            const int l = i ^ j;
            if (l > i) {
                const u64 a = lo[i], b = lo[l];
                const bool sw = a > b;
                lo[i] = sw ? b : a;
                lo[l] = sw ? a : b;
            }
        }
    }
#pragma unroll
    for (int i = 0; i < 16; ++i) list[i] = lo[i];
}

// Drain the per-lane append buffer: sentinel-mask, sort, merge. Uniform,
// branch-free; lanes with cnt==0 merge all-sentinels (no-op).
__device__ __forceinline__ void flush_buf(u64 list[MAXK], u64& wkey, int& cnt,
                                          const u64 (*buf)[BQ], int lane) {
    u64 br[MAXK];
#pragma unroll
    for (int i = 0; i < 16; ++i) {
        const u64 v = buf[i][lane];
        br[i] = (i < cnt) ? v : ~0ull;
    }
    bitonic16(br);
    merge16(list, br);
    wkey = list[15];
    cnt = 0;
}

// k = argmax(kvec)+1 (first index wins), gather preds of selected, mean.
// Identical op order to previous passing rounds.
__device__ __forceinline__ void write_mean(const float* __restrict__ pb,
                                           const float* __restrict__ kvec,
                                           const u64 list[MAXK],
                                           float* __restrict__ op) {
    float bv = kvec[0]; int bi = 0;
#pragma unroll
    for (int i = 1; i < MAXK; ++i) { const float v = kvec[i]; if (v > bv) { bv = v; bi = i; } }
    const int k = bi + 1;
    float sx = 0.f, sy = 0.f, sz = 0.f;
#pragma unroll
    for (int s = 0; s < MAXK; ++s) {
        if (s < k) {
            const int j = (int)(u32)list[s];
            sx = __fadd_rn(sx, pb[j * 3 + 0]);
            sy = __fadd_rn(sy, pb[j * 3 + 1]);
            sz = __fadd_rn(sz, pb[j * 3 + 2]);
        }
    }
    const float fk = (float)k;
    op[0] = __fdiv_rn(sx, fk);
    op[1] = __fdiv_rn(sy, fk);
    op[2] = __fdiv_rn(sz, fk);
}

// Precompute (x, y, z, ||p||^2) per point — same fp32 op order as reference.
__global__ __launch_bounds__(256) void knn_prep(const float* __restrict__ x,
                                                float4* __restrict__ tab) {
    const int i = blockIdx.x * 256 + (int)threadIdx.x;   // 0 .. B*N-1
    const float cx = x[i * 3 + 0], cy = x[i * 3 + 1], cz = x[i * 3 + 2];
    const float sq = __fadd_rn(__fadd_rn(__fmul_rn(cx, cx), __fmul_rn(cy, cy)),
                               __fmul_rn(cz, cz));
    tab[i] = make_float4(cx, cy, cz, sq);
}

template <int SEGS, bool TAB, bool FUSED>
__global__ __launch_bounds__(BQ) void knn_scan(
    const float* __restrict__ x, const float* __restrict__ preds,
    const float* __restrict__ kvec, const float4* __restrict__ tab,
    u64* __restrict__ wkeys, float* __restrict__ out)
{
    constexpr int SEGLEN = NN / SEGS;
    int bid = blockIdx.x;
    const int seg = bid % SEGS;
    bid /= SEGS;
    const int qg = bid % (NN / BQ);
    const int b  = bid / (NN / BQ);
    const int lane = (int)threadIdx.x;
    const int qi = qg * BQ + lane;

    const float* xb = x + (size_t)b * NN * 3;
    const float4* tb = TAB ? (tab + (size_t)b * NN) : nullptr;

    float qx, qy, qz, qsq;
    if (TAB) {
        const float4 qv = tb[qi];
        qx = qv.x; qy = qv.y; qz = qv.z; qsq = qv.w;
    } else {
        qx = xb[qi * 3 + 0]; qy = xb[qi * 3 + 1]; qz = xb[qi * 3 + 2];
        qsq = __fadd_rn(__fadd_rn(__fmul_rn(qx, qx), __fmul_rn(qy, qy)),
                        __fmul_rn(qz, qz));
    }

    __shared__ u64 buf[BUFSLOTS][BQ];    // [slot][lane] -> 2-way banks (free)

    u64 list[MAXK];
#pragma unroll
    for (int s = 0; s < MAXK; ++s) list[s] = ~0ull;
    u64 wkey = ~0ull;
    int cnt = 0;

    const int jbase = seg * SEGLEN;
#pragma unroll 1
    for (int t = 0; t < SEGLEN; t += 4) {
        // Room check for the next 4 appends; flush is wave-uniform.
        if (__any((int)(cnt > BUFSLOTS - 4))) flush_buf(list, wkey, cnt, buf, lane);
#pragma unroll
        for (int u = 0; u < 4; ++u) {
            const int j = jbase + t + u;            // wave-uniform address
            float cx, cy, cz, csq;
            if (TAB) {
                const float4 c = tb[j];
                cx = c.x; cy = c.y; cz = c.z; csq = c.w;
            } else {
                cx = xb[j * 3 + 0]; cy = xb[j * 3 + 1]; cz = xb[j * 3 + 2];
                csq = __fadd_rn(__fadd_rn(__fmul_rn(cx, cx), __fmul_rn(cy, cy)),
                                __fmul_rn(cz, cz));
            }
            // Reference fp32 op order, no FMA contraction.
            const float inner = __fadd_rn(
                __fadd_rn(__fmul_rn(qx, cx), __fmul_rn(qy, cy)),
                __fmul_rn(qz, cz));
            float d2 = __fsub_rn(__fadd_rn(qsq, csq), __fmul_rn(2.0f, inner));
            d2 = fmaxf(d2, 0.0f);
            // Unique lexicographic key: (d2 bits, index). Strict < = top_k tie rule.
            const u64 key = ((u64)__float_as_uint(d2) << 32) | (u32)j;
            buf[cnt][lane] = key;                   // unconditional append write
            cnt += (key < wkey) ? 1 : 0;
        }
    }
    flush_buf(list, wkey, cnt, buf, lane);

    if (FUSED) {
        write_mean(preds + (size_t)b * NN * 3, kvec, list,
                   out + ((size_t)b * NN + qi) * 3);
    } else {
        // [SEGS*16][B*N] layout: coalesced stores here, coalesced loads in merge.
        const size_t q = (size_t)b * NN + qi;
#pragma unroll
        for (int s = 0; s < MAXK; ++s)
            wkeys[(size_t)(seg * MAXK + s) * (BB * NN) + q] = list[s];
    }
}

template <int SEGS>
__global__ __launch_bounds__(BQ) void knn_merge(
    const float* __restrict__ preds, const float* __restrict__ kvec,
    const u64* __restrict__ wkeys, float* __restrict__ out)
{
    const int lane = (int)threadIdx.x;
    const int q = blockIdx.x * BQ + lane;           // 0 .. B*N-1

    __shared__ u64 buf[BUFSLOTS][BQ];

    u64 list[MAXK];
#pragma unroll
    for (int s = 0; s < MAXK; ++s) list[s] = ~0ull;
    u64 wkey = ~0ull;
    int cnt = 0;

#pragma unroll 1
    for (int i = 0; i < SEGS * MAXK; i += 4) {
        if (__any((int)(cnt > BUFSLOTS - 4))) flush_buf(list, wkey, cnt, buf, lane);
#pragma unroll
        for (int u = 0; u < 4; ++u) {
            const u64 key = wkeys[(size_t)(i + u) * (BB * NN) + q];  // coalesced
            buf[cnt][lane] = key;
            cnt += (key < wkey) ? 1 : 0;
        }
    }
    flush_buf(list, wkey, cnt, buf, lane);

    const int b = q / NN;
    write_mean(preds + (size_t)b * NN * 3, kvec, list, out + (size_t)q * 3);
}

extern "C" void kernel_launch(void* const* d_in, const int* in_sizes, int n_in,
                              void* d_out, int out_size, void* d_ws, size_t ws_size,
                              hipStream_t stream) {
    (void)in_sizes; (void)n_in; (void)out_size;
    const float* x     = (const float*)d_in[0];
    const float* preds = (const float*)d_in[1];
    const float* kvec  = (const float*)d_in[2];
    float* out = (float*)d_out;

    const size_t keys8 = 8ull * MAXK * BB * NN * sizeof(u64);   // 33.55 MB
    const size_t keys4 = 4ull * MAXK * BB * NN * sizeof(u64);   // 16.78 MB
    const size_t tabsz = (size_t)BB * NN * sizeof(float4);      // 0.52 MB

    if (ws_size >= keys8 + tabsz) {
        u64* wkeys  = (u64*)d_ws;
        float4* tab = (float4*)((char*)d_ws + keys8);
        knn_prep<<<(BB * NN) / 256, 256, 0, stream>>>(x, tab);
        knn_scan<8, true, false><<<BB * (NN / BQ) * 8, BQ, 0, stream>>>(
            x, preds, kvec, tab, wkeys, out);
        knn_merge<8><<<(BB * NN) / BQ, BQ, 0, stream>>>(preds, kvec, wkeys, out);
    } else if (ws_size >= keys4 + tabsz) {
        u64* wkeys  = (u64*)d_ws;
        float4* tab = (float4*)((char*)d_ws + keys4);
        knn_prep<<<(BB * NN) / 256, 256, 0, stream>>>(x, tab);
        knn_scan<4, true, false><<<BB * (NN / BQ) * 4, BQ, 0, stream>>>(
            x, preds, kvec, tab, wkeys, out);
        knn_merge<4><<<(BB * NN) / BQ, BQ, 0, stream>>>(preds, kvec, wkeys, out);
    } else if (ws_size >= keys4) {
        u64* wkeys = (u64*)d_ws;
        knn_scan<4, false, false><<<BB * (NN / BQ) * 4, BQ, 0, stream>>>(
            x, preds, kvec, nullptr, wkeys, out);
        knn_merge<4><<<(BB * NN) / BQ, BQ, 0, stream>>>(preds, kvec, wkeys, out);
    } else {
        knn_scan<1, false, true><<<BB * (NN / BQ), BQ, 0, stream>>>(
            x, preds, kvec, nullptr, nullptr, out);
    }
}